// Round 5
// baseline (269.585 us; speedup 1.0000x reference)
//
#include <hip/hip_runtime.h>

#define EPS 1e-9f
constexpr int NN = 131072;
constexpr int CD = 64;
constexpr int KK = 32;
constexpr int BB = 16;

// ---- workspace layout (float offsets) ----
constexpr int WS_ENT  = 0;                    // entropy accumulator (1 float)
constexpr int WS_BACC = 16;                   // bacc[B][K][FP]: f 0..63 = x, 64 px, 65 py, 66 |p|^2, 67 = 1
constexpr int FP      = 72;                   // padded feature count
constexpr int WS_BACC_SZ = BB * KK * FP;      // 36864
constexpr int WS_W1T  = WS_BACC + WS_BACC_SZ; // transposed W1 [j][c], 4096
constexpr int WS_TAG  = WS_W1T + 4096;        // int tag per pool block (<=1024)
constexpr int WS_PART = WS_TAG + 1040;        // per-block partials [nblk][68*32]
constexpr int CELLS   = 68 * 32;              // 2176 cells per partial tile

// ---- output layout (float offsets), tuple order of the reference ----
constexpr int OUT_OUT  = 0;                   // [B,K,C] = 32768
constexpr int OUT_S    = BB * KK * CD;        // s [N,K]
constexpr int OUT_SCAL = OUT_S + NN * KK;     // entropy, diversity, spatial, pruning, sparsity, separation
constexpr int OUT_MU   = OUT_SCAL + 6;        // mu [B,K,2]

// one-time transpose of W1 so columns are contiguous (scalar-loadable rows)
__global__ void prep_k(const float* __restrict__ W1, float* __restrict__ ws) {
    int t = blockIdx.x * 256 + threadIdx.x;   // 4096 threads
    int c = t >> 6, j = t & 63;
    ws[WS_W1T + j * 64 + c] = W1[c * 64 + j];
}

// per-node MLP -> gumbel -> softmax -> s ; entropy partial.
// x-rows staged in LDS once (coalesced), then re-read per hidden unit j.
// Round-3/4 evidence: compiler refuses to keep xv[64] in VGPRs (VGPR=56) and
// re-loads x from global 64x -> 2.1 GB L1/L2 traffic, latency-bound.
// LDS row stride 68 floats (272 B): 16B-aligned, rows spread across banks so
// wave64 ds_read_b128 runs at its 8-cyc BW floor.
constexpr int XS_STRIDE = 68;
__global__ __launch_bounds__(128)
void node_k(const float* __restrict__ x,
            const float* __restrict__ u,
            const float* __restrict__ w1t,
            const float* __restrict__ b1,
            const float* __restrict__ W2,
            const float* __restrict__ b2,
            const float* __restrict__ scaling,
            const float* __restrict__ amask,
            float* __restrict__ s_out,
            float* __restrict__ ent_acc) {
    __shared__ float xs[128 * XS_STRIDE];     // 34816 B
    const int t = threadIdx.x;                // 128 threads
    // ---- stage 128 rows of x, fully coalesced float4 loads ----
    const float4* gx = (const float4*)(x + (size_t)blockIdx.x * 128 * 64);
#pragma unroll
    for (int i = 0; i < 16; i++) {
        const int f = i * 128 + t;            // float4 index in the tile
        const int row = f >> 4, c4 = f & 15;
        *(float4*)(xs + row * XS_STRIDE + c4 * 4) = gx[f];
    }
    __syncthreads();

    const int n = blockIdx.x * 128 + t;
    const float* xr = xs + t * XS_STRIDE;
    float logit[32];
#pragma unroll
    for (int k = 0; k < 32; k++) logit[k] = b2[k];
#pragma unroll 2
    for (int j = 0; j < 64; j++) {
        const float* w1r = w1t + j * 64;      // uniform address -> scalar loads
        float p0 = b1[j], p1 = 0.f, p2 = 0.f, p3 = 0.f;
#pragma unroll
        for (int c4 = 0; c4 < 16; c4++) {
            float4 xq = *(const float4*)(xr + c4 * 4);
            p0 = fmaf(xq.x, w1r[c4 * 4 + 0], p0);
            p1 = fmaf(xq.y, w1r[c4 * 4 + 1], p1);
            p2 = fmaf(xq.z, w1r[c4 * 4 + 2], p2);
            p3 = fmaf(xq.w, w1r[c4 * 4 + 3], p3);
        }
        float hj = fmaxf((p0 + p1) + (p2 + p3), 0.f);
        const float* w2r = W2 + j * 32;       // uniform -> scalar loads
#pragma unroll
        for (int k = 0; k < 32; k++) logit[k] = fmaf(hj, w2r[k], logit[k]);
    }
    const float sc = scaling[0];
    const float* ur = u + n * 32;
    float m = -3.0e38f;
#pragma unroll
    for (int k4 = 0; k4 < 8; k4++) {
        float4 uv = *(const float4*)(ur + 4 * k4);
        float us[4] = {uv.x, uv.y, uv.z, uv.w};
#pragma unroll
        for (int q = 0; q < 4; q++) {
            const int k = 4 * k4 + q;
            float l = logit[k] * sc;
            l = (amask[k] == 0.f) ? -1e9f : l;
            float g = -__logf(-__logf(us[q] + EPS) + EPS);
            float z = l + g;                  // TAU = 1
            logit[k] = z;
            m = fmaxf(m, z);
        }
    }
    float e0 = 0.f, e1 = 0.f, e2 = 0.f, e3 = 0.f;
#pragma unroll
    for (int k = 0; k < 32; k += 4) {
        float a = __expf(logit[k] - m);     logit[k] = a;     e0 += a;
        float b = __expf(logit[k + 1] - m); logit[k + 1] = b; e1 += b;
        float c = __expf(logit[k + 2] - m); logit[k + 2] = c; e2 += c;
        float d = __expf(logit[k + 3] - m); logit[k + 3] = d; e3 += d;
    }
    const float inv = 1.f / ((e0 + e1) + (e2 + e3));
    float ent = 0.f;
#pragma unroll
    for (int k = 0; k < 32; k++) {
        float sv = logit[k] * inv;
        logit[k] = sv;
        ent += sv * __logf(sv + EPS);
    }
    float* so = s_out + n * 32;
#pragma unroll
    for (int k4 = 0; k4 < 8; k4++)
        *(float4*)(so + 4 * k4) = make_float4(logit[4 * k4], logit[4 * k4 + 1],
                                              logit[4 * k4 + 2], logit[4 * k4 + 3]);
    // wave-level reduce then one atomic per wave
#pragma unroll
    for (int off = 32; off > 0; off >>= 1) ent += __shfl_down(ent, off, 64);
    if ((t & 63) == 0) atomicAdd(ent_acc, ent);
}

// pooled outer product, feature-split: thread (k, fg) owns features fg*8..fg*8+7
// (+ one extra for fg<4). Per-block partial tile -> plain stores (NO atomics in
// the common path); only mid-block batch boundaries flush via atomics (rare).
__global__ void pool_k(const float* __restrict__ s,
                       const float* __restrict__ x,
                       const float* __restrict__ pos,
                       const int* __restrict__ batch,
                       float* __restrict__ bacc,
                       float* __restrict__ part,
                       int* __restrict__ tags,
                       int npb) {
    const int t = threadIdx.x;
    const int k = t & 31;
    const int fg = t >> 5;              // 0..7
    const int base = blockIdx.x * npb;
    float acc[8];
    float accx = 0.f;                   // fg==0: px, 1: py, 2: |p|^2, 3: sum
#pragma unroll
    for (int f = 0; f < 8; f++) acc[f] = 0.f;
    int cur_b = batch[base];
#pragma unroll 2
    for (int n = base; n < base + npb; n++) {
        const int b = batch[n];         // block-uniform scalar load
        if (b != cur_b) {               // uniform, rare (batch sorted, ~15 blocks total)
            float* dst = bacc + (cur_b * 32 + k) * FP;
#pragma unroll
            for (int f = 0; f < 8; f++) { atomicAdd(dst + fg * 8 + f, acc[f]); acc[f] = 0.f; }
            if (fg < 4) { atomicAdd(dst + 64 + fg, accx); accx = 0.f; }
            cur_b = b;
        }
        const float sv = s[n * 32 + k]; // coalesced across the wave
        const float4 v0 = *(const float4*)(x + n * 64 + fg * 8);      // broadcast per fg
        const float4 v1 = *(const float4*)(x + n * 64 + fg * 8 + 4);
        acc[0] = fmaf(sv, v0.x, acc[0]);
        acc[1] = fmaf(sv, v0.y, acc[1]);
        acc[2] = fmaf(sv, v0.z, acc[2]);
        acc[3] = fmaf(sv, v0.w, acc[3]);
        acc[4] = fmaf(sv, v1.x, acc[4]);
        acc[5] = fmaf(sv, v1.y, acc[5]);
        acc[6] = fmaf(sv, v1.z, acc[6]);
        acc[7] = fmaf(sv, v1.w, acc[7]);
        if (fg < 4) {                   // wave-uniform branch
            float2 p = *(const float2*)(pos + n * 2);                 // broadcast
            float e = (fg == 0) ? p.x : (fg == 1) ? p.y
                    : (fg == 2) ? (p.x * p.x + p.y * p.y) : 1.f;
            accx = fmaf(sv, e, accx);
        }
    }
    // plain coalesced partial store: layout part[blk][f*32 + k]
    float* pp = part + (size_t)blockIdx.x * CELLS;
#pragma unroll
    for (int f = 0; f < 8; f++) pp[(fg * 8 + f) * 32 + k] = acc[f];
    if (fg < 4) pp[(64 + fg) * 32 + k] = accx;
    if (t == 0) tags[blockIdx.x] = cur_b;
}

// one thread per (b,k,f) cell. tags[] is NON-DECREASING (batch sorted, each
// partial tile belongs wholly to its end-tag) -> binary-search the tag range
// for b and read only ~nblk/16 tiles instead of scanning all of them.
__global__ void reduce_k(const float* __restrict__ part,
                         const int* __restrict__ tags,
                         float* __restrict__ bacc,
                         float* __restrict__ outp,
                         int nblk) {
    const int b = blockIdx.x;                   // 0..15
    const int cell = blockIdx.y * 256 + threadIdx.x;
    if (cell >= CELLS) return;
    const int k = cell & 31, f = cell >> 5;
    int lo = 0, hi = nblk;                      // lo = first tag >= b
    while (lo < hi) { int mid = (lo + hi) >> 1; if (tags[mid] < b) lo = mid + 1; else hi = mid; }
    int lo2 = lo, hi2 = nblk;                   // lo2..: first tag >= b+1
    while (lo2 < hi2) { int mid = (lo2 + hi2) >> 1; if (tags[mid] < b + 1) lo2 = mid + 1; else hi2 = mid; }
    float v = 0.f;
    for (int blk = lo; blk < lo2; blk++)        // coalesced: cells contiguous per blk
        v += part[(size_t)blk * CELLS + cell];
    const int idx = (b * 32 + k) * FP + f;
    const float tot = bacc[idx] + v;            // + boundary flushes
    bacc[idx] = tot;
    if (f < 64) outp[OUT_OUT + ((b * 32 + k) << 6) + f] = tot;
}

// single block: mu + all six scalars
__global__ void fin_k(const float* __restrict__ ws,
                      const float* __restrict__ amask,
                      float* __restrict__ outp) {
    const int t = threadIdx.x;
    const float* bacc = ws + WS_BACC;
    __shared__ float mu_s[BB * KK * 2];
    for (int idx = t; idx < BB * KK * 2; idx += 256) {
        int bk = idx >> 1, d = idx & 1;
        float v = bacc[bk * FP + 64 + d] / (bacc[bk * FP + 67] + EPS);
        mu_s[idx] = v;
        outp[OUT_MU + idx] = v;
    }
    __shared__ float kred[32][4];
    if (t < 32) {
        float S = 0, px = 0, py = 0, sq = 0;
        for (int b = 0; b < 16; b++) {
            const float* pp = bacc + (b * 32 + t) * FP;
            S += pp[67]; px += pp[64]; py += pp[65]; sq += pp[66];
        }
        float avg = S / (float)NN;
        float am = amask[t];
        float ssum = S + EPS;
        float mx = px / ssum, my = py / ssum;
        kred[t][0] = avg * __logf(avg + EPS);          // diversity term
        kred[t][1] = fabsf(avg * (1.f - am));          // pruning term
        kred[t][2] = sq / ssum - mx * mx - my * my;    // spatial var
        kred[t][3] = am;                               // sparsity term
    }
    __syncthreads();
    float sep = 0.f;
    for (int idx = t; idx < BB * KK * KK; idx += 256) {
        int b = idx >> 10, i = (idx >> 5) & 31, j = idx & 31;
        if (i != j) {
            float dx = mu_s[(b * 32 + i) * 2 + 0] - mu_s[(b * 32 + j) * 2 + 0];
            float dy = mu_s[(b * 32 + i) * 2 + 1] - mu_s[(b * 32 + j) * 2 + 1];
            sep += 1.f / (dx * dx + dy * dy + 1.f);
        }
    }
    __shared__ float red[256];
    red[t] = sep;
    __syncthreads();
    for (int s2 = 128; s2 > 0; s2 >>= 1) {
        if (t < s2) red[t] += red[t + s2];
        __syncthreads();
    }
    if (t == 0) {
        float div = 0, pru = 0, spa = 0, spar = 0;
        for (int kq = 0; kq < 32; kq++) {
            div += kred[kq][0]; pru += kred[kq][1];
            spa += kred[kq][2]; spar += kred[kq][3];
        }
        outp[OUT_SCAL + 0] = -ws[WS_ENT] / (float)NN;        // entropy
        outp[OUT_SCAL + 1] = div;                            // diversity
        outp[OUT_SCAL + 2] = spa / 32.f;                     // spatial
        outp[OUT_SCAL + 3] = pru / 32.f;                     // pruning
        outp[OUT_SCAL + 4] = spar / 32.f;                    // sparsity
        outp[OUT_SCAL + 5] = red[0] / (32.f * 31.f + EPS);   // separation
    }
}

extern "C" void kernel_launch(void* const* d_in, const int* in_sizes, int n_in,
                              void* d_out, int out_size, void* d_ws, size_t ws_size,
                              hipStream_t stream) {
    const float* x       = (const float*)d_in[0];
    const int*   batch   = (const int*)d_in[1];
    const float* pos     = (const float*)d_in[2];
    const float* u       = (const float*)d_in[3];
    const float* W1      = (const float*)d_in[4];
    const float* b1      = (const float*)d_in[5];
    const float* W2      = (const float*)d_in[6];
    const float* b2      = (const float*)d_in[7];
    const float* scaling = (const float*)d_in[8];
    const float* amask   = (const float*)d_in[9];
    float* outp = (float*)d_out;
    float* ws   = (float*)d_ws;

    // choose nodes-per-block so the partial buffer fits ws (prefers 1024 blocks)
    int npb = 128;
    while (npb < NN &&
           ws_size < ((size_t)WS_PART + (size_t)(NN / npb) * CELLS) * sizeof(float))
        npb <<= 1;
    const int nblk = NN / npb;

    hipMemsetAsync(ws, 0, (size_t)(WS_BACC + WS_BACC_SZ) * sizeof(float), stream);
    prep_k<<<16, 256, 0, stream>>>(W1, ws);
    node_k<<<NN / 128, 128, 0, stream>>>(x, u, ws + WS_W1T, b1, W2, b2, scaling, amask,
                                         outp + OUT_S, ws + WS_ENT);
    pool_k<<<nblk, 256, 0, stream>>>(outp + OUT_S, x, pos, batch,
                                     ws + WS_BACC, ws + WS_PART, (int*)(ws + WS_TAG), npb);
    reduce_k<<<dim3(BB, (CELLS + 255) / 256), 256, 0, stream>>>(
        ws + WS_PART, (const int*)(ws + WS_TAG), ws + WS_BACC, outp, nblk);
    fin_k<<<1, 256, 0, stream>>>(ws, amask, outp);
}

// Round 6
// 246.038 us; speedup vs baseline: 1.0957x; 1.0957x over previous
//
#include <hip/hip_runtime.h>

#define EPS 1e-9f
constexpr int NN = 131072;
constexpr int CD = 64;
constexpr int KK = 32;
constexpr int BB = 16;

// ---- workspace layout (float offsets) ----
constexpr int WS_ENT  = 0;                    // entropy accumulator (1 float)
constexpr int WS_BACC = 16;                   // bacc[B][K][FP]: f 0..63 = x, 64 px, 65 py, 66 |p|^2, 67 = 1
constexpr int FP      = 72;                   // padded feature count
constexpr int WS_BACC_SZ = BB * KK * FP;      // 36864
constexpr int WS_TAG  = WS_BACC + WS_BACC_SZ; // int tag per pool block (<=1024)
constexpr int WS_PART = WS_TAG + 1040;        // per-block partials [nblk][68*32]
constexpr int CELLS   = 68 * 32;              // 2176 cells per partial tile

// ---- output layout (float offsets), tuple order of the reference ----
constexpr int OUT_OUT  = 0;                   // [B,K,C] = 32768
constexpr int OUT_S    = BB * KK * CD;        // s [N,K]
constexpr int OUT_SCAL = OUT_S + NN * KK;     // entropy, diversity, spatial, pruning, sparsity, separation
constexpr int OUT_MU   = OUT_SCAL + 6;        // mu [B,K,2]

// per-node MLP -> gumbel -> softmax -> s ; entropy partial.
// j-BLOCKED: 16 hidden units per x-element read. Rounds 3-5 showed the
// per-j full-row re-read (64x, 2.1 GB) is the bottleneck regardless of
// whether x sits in LDS or L1; blocking cuts re-reads to 4x (134 MB).
// W1 is consumed in its ORIGINAL [c][j] layout: W1[c][jb*16..+16) is 16
// contiguous floats -> one s_load_dwordx16 per (c, jb). No transpose.
__global__ __launch_bounds__(256, 4)
void node_k(const float* __restrict__ x,
            const float* __restrict__ u,
            const float* __restrict__ W1,
            const float* __restrict__ b1,
            const float* __restrict__ W2,
            const float* __restrict__ b2,
            const float* __restrict__ scaling,
            const float* __restrict__ amask,
            float* __restrict__ s_out,
            float* __restrict__ ent_acc) {
    const int n = blockIdx.x * 256 + threadIdx.x;
    const float* xr = x + (size_t)n * 64;
    float logit[32];
#pragma unroll
    for (int k = 0; k < 32; k++) logit[k] = b2[k];

    for (int jb = 0; jb < 4; jb++) {          // 4 blocks of 16 hidden units
        float h[16];
#pragma unroll
        for (int jj = 0; jj < 16; jj++) h[jj] = b1[jb * 16 + jj];
#pragma unroll
        for (int c4 = 0; c4 < 16; c4++) {
            const float4 xq = *(const float4*)(xr + c4 * 4);
            const float xs4[4] = {xq.x, xq.y, xq.z, xq.w};
#pragma unroll
            for (int q = 0; q < 4; q++) {
                const float xc = xs4[q];
                const float* w1r = W1 + (c4 * 4 + q) * 64 + jb * 16;  // uniform -> s_load_dwordx16
#pragma unroll
                for (int jj = 0; jj < 16; jj++)
                    h[jj] = fmaf(xc, w1r[jj], h[jj]);
            }
        }
#pragma unroll
        for (int jj = 0; jj < 16; jj++) {
            const float hj = fmaxf(h[jj], 0.f);
            const float* w2r = W2 + (jb * 16 + jj) * 32;              // uniform -> s_load
#pragma unroll
            for (int k = 0; k < 32; k++)
                logit[k] = fmaf(hj, w2r[k], logit[k]);
        }
    }

    const float sc = scaling[0];
    const float* ur = u + (size_t)n * 32;
    float m = -3.0e38f;
#pragma unroll
    for (int k4 = 0; k4 < 8; k4++) {
        float4 uv = *(const float4*)(ur + 4 * k4);
        float us[4] = {uv.x, uv.y, uv.z, uv.w};
#pragma unroll
        for (int q = 0; q < 4; q++) {
            const int k = 4 * k4 + q;
            float l = logit[k] * sc;
            l = (amask[k] == 0.f) ? -1e9f : l;
            float g = -__logf(-__logf(us[q] + EPS) + EPS);
            float z = l + g;                  // TAU = 1
            logit[k] = z;
            m = fmaxf(m, z);
        }
    }
    float e0 = 0.f, e1 = 0.f, e2 = 0.f, e3 = 0.f;
#pragma unroll
    for (int k = 0; k < 32; k += 4) {
        float a = __expf(logit[k] - m);     logit[k] = a;     e0 += a;
        float b = __expf(logit[k + 1] - m); logit[k + 1] = b; e1 += b;
        float c = __expf(logit[k + 2] - m); logit[k + 2] = c; e2 += c;
        float d = __expf(logit[k + 3] - m); logit[k + 3] = d; e3 += d;
    }
    const float inv = 1.f / ((e0 + e1) + (e2 + e3));
    float ent = 0.f;
#pragma unroll
    for (int k = 0; k < 32; k++) {
        float sv = logit[k] * inv;
        logit[k] = sv;
        ent += sv * __logf(sv + EPS);
    }
    float* so = s_out + (size_t)n * 32;
#pragma unroll
    for (int k4 = 0; k4 < 8; k4++)
        *(float4*)(so + 4 * k4) = make_float4(logit[4 * k4], logit[4 * k4 + 1],
                                              logit[4 * k4 + 2], logit[4 * k4 + 3]);
    // wave-level reduce then one atomic per wave
#pragma unroll
    for (int off = 32; off > 0; off >>= 1) ent += __shfl_down(ent, off, 64);
    if ((threadIdx.x & 63) == 0) atomicAdd(ent_acc, ent);
}

// pooled outer product, feature-split: thread (k, fg) owns features fg*8..fg*8+7
// (+ one extra for fg<4). Per-block partial tile -> plain stores (NO atomics in
// the common path); only mid-block batch boundaries flush via atomics (rare).
__global__ void pool_k(const float* __restrict__ s,
                       const float* __restrict__ x,
                       const float* __restrict__ pos,
                       const int* __restrict__ batch,
                       float* __restrict__ bacc,
                       float* __restrict__ part,
                       int* __restrict__ tags,
                       int npb) {
    const int t = threadIdx.x;
    const int k = t & 31;
    const int fg = t >> 5;              // 0..7
    const int base = blockIdx.x * npb;
    float acc[8];
    float accx = 0.f;                   // fg==0: px, 1: py, 2: |p|^2, 3: sum
#pragma unroll
    for (int f = 0; f < 8; f++) acc[f] = 0.f;
    int cur_b = batch[base];
#pragma unroll 2
    for (int n = base; n < base + npb; n++) {
        const int b = batch[n];         // block-uniform scalar load
        if (b != cur_b) {               // uniform, rare (batch sorted, ~15 blocks total)
            float* dst = bacc + (cur_b * 32 + k) * FP;
#pragma unroll
            for (int f = 0; f < 8; f++) { atomicAdd(dst + fg * 8 + f, acc[f]); acc[f] = 0.f; }
            if (fg < 4) { atomicAdd(dst + 64 + fg, accx); accx = 0.f; }
            cur_b = b;
        }
        const float sv = s[n * 32 + k]; // coalesced across the wave
        const float4 v0 = *(const float4*)(x + n * 64 + fg * 8);      // broadcast per fg
        const float4 v1 = *(const float4*)(x + n * 64 + fg * 8 + 4);
        acc[0] = fmaf(sv, v0.x, acc[0]);
        acc[1] = fmaf(sv, v0.y, acc[1]);
        acc[2] = fmaf(sv, v0.z, acc[2]);
        acc[3] = fmaf(sv, v0.w, acc[3]);
        acc[4] = fmaf(sv, v1.x, acc[4]);
        acc[5] = fmaf(sv, v1.y, acc[5]);
        acc[6] = fmaf(sv, v1.z, acc[6]);
        acc[7] = fmaf(sv, v1.w, acc[7]);
        if (fg < 4) {                   // wave-uniform branch
            float2 p = *(const float2*)(pos + n * 2);                 // broadcast
            float e = (fg == 0) ? p.x : (fg == 1) ? p.y
                    : (fg == 2) ? (p.x * p.x + p.y * p.y) : 1.f;
            accx = fmaf(sv, e, accx);
        }
    }
    // plain coalesced partial store: layout part[blk][f*32 + k]
    float* pp = part + (size_t)blockIdx.x * CELLS;
#pragma unroll
    for (int f = 0; f < 8; f++) pp[(fg * 8 + f) * 32 + k] = acc[f];
    if (fg < 4) pp[(64 + fg) * 32 + k] = accx;
    if (t == 0) tags[blockIdx.x] = cur_b;
}

// one thread per (b,k,f) cell. tags[] is NON-DECREASING (batch sorted, each
// partial tile belongs wholly to its end-tag) -> binary-search the tag range
// for b and read only ~nblk/16 tiles instead of scanning all of them.
__global__ void reduce_k(const float* __restrict__ part,
                         const int* __restrict__ tags,
                         float* __restrict__ bacc,
                         float* __restrict__ outp,
                         int nblk) {
    const int b = blockIdx.x;                   // 0..15
    const int cell = blockIdx.y * 256 + threadIdx.x;
    if (cell >= CELLS) return;
    const int k = cell & 31, f = cell >> 5;
    int lo = 0, hi = nblk;                      // lo = first tag >= b
    while (lo < hi) { int mid = (lo + hi) >> 1; if (tags[mid] < b) lo = mid + 1; else hi = mid; }
    int lo2 = lo, hi2 = nblk;                   // lo2..: first tag >= b+1
    while (lo2 < hi2) { int mid = (lo2 + hi2) >> 1; if (tags[mid] < b + 1) lo2 = mid + 1; else hi2 = mid; }
    float v = 0.f;
    for (int blk = lo; blk < lo2; blk++)        // coalesced: cells contiguous per blk
        v += part[(size_t)blk * CELLS + cell];
    const int idx = (b * 32 + k) * FP + f;
    const float tot = bacc[idx] + v;            // + boundary flushes
    bacc[idx] = tot;
    if (f < 64) outp[OUT_OUT + ((b * 32 + k) << 6) + f] = tot;
}

// single block: mu + all six scalars
__global__ void fin_k(const float* __restrict__ ws,
                      const float* __restrict__ amask,
                      float* __restrict__ outp) {
    const int t = threadIdx.x;
    const float* bacc = ws + WS_BACC;
    __shared__ float mu_s[BB * KK * 2];
    for (int idx = t; idx < BB * KK * 2; idx += 256) {
        int bk = idx >> 1, d = idx & 1;
        float v = bacc[bk * FP + 64 + d] / (bacc[bk * FP + 67] + EPS);
        mu_s[idx] = v;
        outp[OUT_MU + idx] = v;
    }
    __shared__ float kred[32][4];
    if (t < 32) {
        float S = 0, px = 0, py = 0, sq = 0;
        for (int b = 0; b < 16; b++) {
            const float* pp = bacc + (b * 32 + t) * FP;
            S += pp[67]; px += pp[64]; py += pp[65]; sq += pp[66];
        }
        float avg = S / (float)NN;
        float am = amask[t];
        float ssum = S + EPS;
        float mx = px / ssum, my = py / ssum;
        kred[t][0] = avg * __logf(avg + EPS);          // diversity term
        kred[t][1] = fabsf(avg * (1.f - am));          // pruning term
        kred[t][2] = sq / ssum - mx * mx - my * my;    // spatial var
        kred[t][3] = am;                               // sparsity term
    }
    __syncthreads();
    float sep = 0.f;
    for (int idx = t; idx < BB * KK * KK; idx += 256) {
        int b = idx >> 10, i = (idx >> 5) & 31, j = idx & 31;
        if (i != j) {
            float dx = mu_s[(b * 32 + i) * 2 + 0] - mu_s[(b * 32 + j) * 2 + 0];
            float dy = mu_s[(b * 32 + i) * 2 + 1] - mu_s[(b * 32 + j) * 2 + 1];
            sep += 1.f / (dx * dx + dy * dy + 1.f);
        }
    }
    __shared__ float red[256];
    red[t] = sep;
    __syncthreads();
    for (int s2 = 128; s2 > 0; s2 >>= 1) {
        if (t < s2) red[t] += red[t + s2];
        __syncthreads();
    }
    if (t == 0) {
        float div = 0, pru = 0, spa = 0, spar = 0;
        for (int kq = 0; kq < 32; kq++) {
            div += kred[kq][0]; pru += kred[kq][1];
            spa += kred[kq][2]; spar += kred[kq][3];
        }
        outp[OUT_SCAL + 0] = -ws[WS_ENT] / (float)NN;        // entropy
        outp[OUT_SCAL + 1] = div;                            // diversity
        outp[OUT_SCAL + 2] = spa / 32.f;                     // spatial
        outp[OUT_SCAL + 3] = pru / 32.f;                     // pruning
        outp[OUT_SCAL + 4] = spar / 32.f;                    // sparsity
        outp[OUT_SCAL + 5] = red[0] / (32.f * 31.f + EPS);   // separation
    }
}

extern "C" void kernel_launch(void* const* d_in, const int* in_sizes, int n_in,
                              void* d_out, int out_size, void* d_ws, size_t ws_size,
                              hipStream_t stream) {
    const float* x       = (const float*)d_in[0];
    const int*   batch   = (const int*)d_in[1];
    const float* pos     = (const float*)d_in[2];
    const float* u       = (const float*)d_in[3];
    const float* W1      = (const float*)d_in[4];
    const float* b1      = (const float*)d_in[5];
    const float* W2      = (const float*)d_in[6];
    const float* b2      = (const float*)d_in[7];
    const float* scaling = (const float*)d_in[8];
    const float* amask   = (const float*)d_in[9];
    float* outp = (float*)d_out;
    float* ws   = (float*)d_ws;

    // choose nodes-per-block so the partial buffer fits ws (prefers 1024 blocks)
    int npb = 128;
    while (npb < NN &&
           ws_size < ((size_t)WS_PART + (size_t)(NN / npb) * CELLS) * sizeof(float))
        npb <<= 1;
    const int nblk = NN / npb;

    hipMemsetAsync(ws, 0, (size_t)(WS_BACC + WS_BACC_SZ) * sizeof(float), stream);
    node_k<<<NN / 256, 256, 0, stream>>>(x, u, W1, b1, W2, b2, scaling, amask,
                                         outp + OUT_S, ws + WS_ENT);
    pool_k<<<nblk, 256, 0, stream>>>(outp + OUT_S, x, pos, batch,
                                     ws + WS_BACC, ws + WS_PART, (int*)(ws + WS_TAG), npb);
    reduce_k<<<dim3(BB, (CELLS + 255) / 256), 256, 0, stream>>>(
        ws + WS_PART, (const int*)(ws + WS_TAG), ws + WS_BACC, outp, nblk);
    fin_k<<<1, 256, 0, stream>>>(ws, amask, outp);
}

// Round 7
// 220.024 us; speedup vs baseline: 1.2253x; 1.1182x over previous
//
#include <hip/hip_runtime.h>

#define EPS 1e-9f
constexpr int NN = 131072;
constexpr int CD = 64;
constexpr int KK = 32;
constexpr int BB = 16;

typedef __attribute__((ext_vector_type(8))) short short8;   // 8 bf16 (4 VGPRs)
typedef __attribute__((ext_vector_type(4))) float f32x4;

// ---- workspace layout (float offsets) ----
constexpr int WS_ENT  = 0;                    // entropy accumulator
constexpr int WS_BACC = 16;                   // bacc[B][K][FP]
constexpr int FP      = 72;
constexpr int WS_BACC_SZ = BB * KK * FP;      // 36864
constexpr int WS_W1F  = WS_BACC + WS_BACC_SZ; // 4096 ushort (2048 fl): W1 MFMA frags
constexpr int WS_W2F  = WS_W1F + 2048;        // 2048 ushort (1024 fl): W2 frags (scaled)
constexpr int WS_B2F  = WS_W2F + 1024;        // 32 fl: b2*sc with mask folded
constexpr int WS_TAG  = WS_B2F + 32;          // 1024 int tags
constexpr int WS_PART = 41024;                // per-block partials [nblk][68*32]
constexpr int CELLS   = 68 * 32;

// ---- output layout (float offsets) ----
constexpr int OUT_OUT  = 0;                   // [B,K,C]
constexpr int OUT_S    = BB * KK * CD;        // s [N,K]
constexpr int OUT_SCAL = OUT_S + NN * KK;     // 6 scalars
constexpr int OUT_MU   = OUT_SCAL + 6;        // mu [B,K,2]

__device__ __forceinline__ unsigned short f2bf(float f) {   // RNE float->bf16
    unsigned b = __builtin_bit_cast(unsigned, f);
    b += 0x7fffu + ((b >> 16) & 1u);
    return (unsigned short)(b >> 16);
}

// Pre-pack W1/W2 into per-lane MFMA fragment order (so node_k loads frags as
// one coalesced 16B read/lane). k-mapping: lane l=(idx>>3)&63, e=idx&7 holds
// k = (l>>4)*8+e; N-col = l&15. A uses the SAME k-mapping -> sum over k is
// mapping-invariant. scaling and active_mask are folded into W2/b2 here.
__global__ void prep_k(const float* __restrict__ W1, const float* __restrict__ W2,
                       const float* __restrict__ b2, const float* __restrict__ scaling,
                       const float* __restrict__ amask, float* __restrict__ ws) {
    const int t = threadIdx.x;
    const float sc = scaling[0];
    unsigned short* w1f = (unsigned short*)(ws + WS_W1F);
    for (int idx = t; idx < 4096; idx += 256) {             // f = nt*2+ks, nt 0..3
        int e = idx & 7, lane = (idx >> 3) & 63, f = idx >> 9;
        int nt = f >> 1, ks = f & 1;
        int j = nt * 16 + (lane & 15);
        int c = ks * 32 + (lane >> 4) * 8 + e;
        w1f[idx] = f2bf(W1[c * 64 + j]);
    }
    unsigned short* w2f = (unsigned short*)(ws + WS_W2F);
    for (int idx = t; idx < 2048; idx += 256) {             // f = nt*2+ks, nt 0..1
        int e = idx & 7, lane = (idx >> 3) & 63, f = idx >> 9;
        int nt = f >> 1, ks = f & 1;
        int j = nt * 16 + (lane & 15);
        int c = ks * 32 + (lane >> 4) * 8 + e;
        w2f[idx] = f2bf(sc * W2[c * 32 + j]);
    }
    if (t < 32) ws[WS_B2F + t] = (amask[t] == 0.f) ? -1e9f : b2[t] * sc;
}

// MFMA node kernel: block = 64 nodes, 4 waves x 16-node tiles.
// GEMM1 (X@W1, 8 mfma) -> relu -> H in LDS (bf16, chunk-XOR swizzle vs the
// stride-128B bank conflict) -> GEMM2 (H@W2sc, 4 mfma) -> logits in LDS ->
// 4-threads-per-node gumbel/softmax.
__global__ __launch_bounds__(256)
void node_k(const float* __restrict__ x, const float* __restrict__ u,
            const float* __restrict__ b1, const float* __restrict__ ws,
            float* __restrict__ s_out, float* __restrict__ ent_acc) {
    __shared__ unsigned short Hlds[4096];     // [wave][16 rows][64] bf16, swizzled
    __shared__ float Llds[64 * 33];           // logits [64 nodes][32], pad 33
    __shared__ float entred[4];
    const int t = threadIdx.x;
    const int w = t >> 6, l = t & 63, lj = l & 15, lg = l >> 4;
    const unsigned short* w1f = (const unsigned short*)(ws + WS_W1F);
    const unsigned short* w2f = (const unsigned short*)(ws + WS_W2F);
    const float* b2f = ws + WS_B2F;

    // ---- A frags: x rows. lane: node row = lj, k = lg*8+e (same mapping as prep)
    const int node = blockIdx.x * 64 + w * 16 + lj;
    const float* xr = x + (size_t)node * 64 + lg * 8;
    short8 a0, a1;
    {
        float4 p0 = *(const float4*)xr;
        float4 p1 = *(const float4*)(xr + 4);
        float4 p2 = *(const float4*)(xr + 32);
        float4 p3 = *(const float4*)(xr + 36);
        a0[0] = f2bf(p0.x); a0[1] = f2bf(p0.y); a0[2] = f2bf(p0.z); a0[3] = f2bf(p0.w);
        a0[4] = f2bf(p1.x); a0[5] = f2bf(p1.y); a0[6] = f2bf(p1.z); a0[7] = f2bf(p1.w);
        a1[0] = f2bf(p2.x); a1[1] = f2bf(p2.y); a1[2] = f2bf(p2.z); a1[3] = f2bf(p2.w);
        a1[4] = f2bf(p3.x); a1[5] = f2bf(p3.y); a1[6] = f2bf(p3.z); a1[7] = f2bf(p3.w);
    }
    // ---- GEMM1: 4 col-tiles of W1
    f32x4 hacc[4];
#pragma unroll
    for (int nt = 0; nt < 4; nt++) {
        f32x4 acc = {0.f, 0.f, 0.f, 0.f};
        short8 b0 = *(const short8*)(w1f + (nt * 2 + 0) * 512 + l * 8);
        short8 b1v = *(const short8*)(w1f + (nt * 2 + 1) * 512 + l * 8);
        acc = __builtin_amdgcn_mfma_f32_16x16x32_bf16(a0, b0, acc, 0, 0, 0);
        acc = __builtin_amdgcn_mfma_f32_16x16x32_bf16(a1, b1v, acc, 0, 0, 0);
        hacc[nt] = acc;
    }
    // ---- relu + bias, H -> LDS. D layout: row=(lg*4+q) [node-sub], col=nt*16+lj [j]
#pragma unroll
    for (int nt = 0; nt < 4; nt++) {
        const float bias = b1[nt * 16 + lj];
#pragma unroll
        for (int q = 0; q < 4; q++) {
            const int r = lg * 4 + q;
            const float hv = fmaxf(hacc[nt][q] + bias, 0.f);
            const int bo = (nt * 32 + lj * 2) ^ ((r & 7) << 4);   // swizzle 16B chunks
            Hlds[w * 1024 + r * 64 + (bo >> 1)] = f2bf(hv);
        }
    }
    // ---- A2 frags from H (wave-internal dep; compiler inserts lgkmcnt)
    short8 a20, a21;
    {
        const int base = w * 1024 + lj * 64;                      // A2 row = lj
        a20 = *(const short8*)(Hlds + base + ((lg ^ (lj & 7)) << 3));
        a21 = *(const short8*)(Hlds + base + (((4 + lg) ^ (lj & 7)) << 3));
    }
    // ---- GEMM2: 2 col-tiles of W2 (pre-scaled)
#pragma unroll
    for (int nt = 0; nt < 2; nt++) {
        f32x4 acc = {0.f, 0.f, 0.f, 0.f};
        short8 b0 = *(const short8*)(w2f + (nt * 2 + 0) * 512 + l * 8);
        short8 b1v = *(const short8*)(w2f + (nt * 2 + 1) * 512 + l * 8);
        acc = __builtin_amdgcn_mfma_f32_16x16x32_bf16(a20, b0, acc, 0, 0, 0);
        acc = __builtin_amdgcn_mfma_f32_16x16x32_bf16(a21, b1v, acc, 0, 0, 0);
        const float bb = b2f[nt * 16 + lj];                       // mask+scale folded
#pragma unroll
        for (int q = 0; q < 4; q++)
            Llds[(w * 16 + lg * 4 + q) * 33 + nt * 16 + lj] = acc[q] + bb;
    }
    __syncthreads();

    // ---- gumbel + softmax: 4 threads per node, 8 k each
    const int nl = t >> 2, sub = t & 3;
    const int n = blockIdx.x * 64 + nl;
    const float* Lr = &Llds[nl * 33 + sub * 8];
    const float* ur = u + (size_t)n * 32 + sub * 8;
    float4 u0 = *(const float4*)ur, u1 = *(const float4*)(ur + 4);
    float uu[8] = {u0.x, u0.y, u0.z, u0.w, u1.x, u1.y, u1.z, u1.w};
    float z[8];
    float m = -3.0e38f;
#pragma unroll
    for (int i = 0; i < 8; i++) {
        float g = -__logf(-__logf(uu[i] + EPS) + EPS);
        z[i] = Lr[i] + g;                      // TAU = 1
        m = fmaxf(m, z[i]);
    }
    m = fmaxf(m, __shfl_xor(m, 1, 64));
    m = fmaxf(m, __shfl_xor(m, 2, 64));
    float es = 0.f;
#pragma unroll
    for (int i = 0; i < 8; i++) { z[i] = __expf(z[i] - m); es += z[i]; }
    es += __shfl_xor(es, 1, 64);
    es += __shfl_xor(es, 2, 64);
    const float inv = 1.f / es;
    float ent = 0.f;
#pragma unroll
    for (int i = 0; i < 8; i++) {
        float sv = z[i] * inv;
        z[i] = sv;
        ent += sv * __logf(sv + EPS);
    }
    float* so = s_out + (size_t)n * 32 + sub * 8;
    *(float4*)so = make_float4(z[0], z[1], z[2], z[3]);
    *(float4*)(so + 4) = make_float4(z[4], z[5], z[6], z[7]);
#pragma unroll
    for (int off = 32; off > 0; off >>= 1) ent += __shfl_down(ent, off, 64);
    if (l == 0) entred[w] = ent;
    __syncthreads();
    if (t == 0) atomicAdd(ent_acc, entred[0] + entred[1] + entred[2] + entred[3]);
}

// pooled outer product, feature-split (unchanged from round 5)
__global__ void pool_k(const float* __restrict__ s,
                       const float* __restrict__ x,
                       const float* __restrict__ pos,
                       const int* __restrict__ batch,
                       float* __restrict__ bacc,
                       float* __restrict__ part,
                       int* __restrict__ tags,
                       int npb) {
    const int t = threadIdx.x;
    const int k = t & 31;
    const int fg = t >> 5;
    const int base = blockIdx.x * npb;
    float acc[8];
    float accx = 0.f;
#pragma unroll
    for (int f = 0; f < 8; f++) acc[f] = 0.f;
    int cur_b = batch[base];
#pragma unroll 2
    for (int n = base; n < base + npb; n++) {
        const int b = batch[n];
        if (b != cur_b) {
            float* dst = bacc + (cur_b * 32 + k) * FP;
#pragma unroll
            for (int f = 0; f < 8; f++) { atomicAdd(dst + fg * 8 + f, acc[f]); acc[f] = 0.f; }
            if (fg < 4) { atomicAdd(dst + 64 + fg, accx); accx = 0.f; }
            cur_b = b;
        }
        const float sv = s[n * 32 + k];
        const float4 v0 = *(const float4*)(x + n * 64 + fg * 8);
        const float4 v1 = *(const float4*)(x + n * 64 + fg * 8 + 4);
        acc[0] = fmaf(sv, v0.x, acc[0]);
        acc[1] = fmaf(sv, v0.y, acc[1]);
        acc[2] = fmaf(sv, v0.z, acc[2]);
        acc[3] = fmaf(sv, v0.w, acc[3]);
        acc[4] = fmaf(sv, v1.x, acc[4]);
        acc[5] = fmaf(sv, v1.y, acc[5]);
        acc[6] = fmaf(sv, v1.z, acc[6]);
        acc[7] = fmaf(sv, v1.w, acc[7]);
        if (fg < 4) {
            float2 p = *(const float2*)(pos + n * 2);
            float e = (fg == 0) ? p.x : (fg == 1) ? p.y
                    : (fg == 2) ? (p.x * p.x + p.y * p.y) : 1.f;
            accx = fmaf(sv, e, accx);
        }
    }
    float* pp = part + (size_t)blockIdx.x * CELLS;
#pragma unroll
    for (int f = 0; f < 8; f++) pp[(fg * 8 + f) * 32 + k] = acc[f];
    if (fg < 4) pp[(64 + fg) * 32 + k] = accx;
    if (t == 0) tags[blockIdx.x] = cur_b;
}

// per-(b,k,f) cell partial reduce with binary-searched tag range (unchanged)
__global__ void reduce_k(const float* __restrict__ part,
                         const int* __restrict__ tags,
                         float* __restrict__ bacc,
                         float* __restrict__ outp,
                         int nblk) {
    const int b = blockIdx.x;
    const int cell = blockIdx.y * 256 + threadIdx.x;
    if (cell >= CELLS) return;
    const int k = cell & 31, f = cell >> 5;
    int lo = 0, hi = nblk;
    while (lo < hi) { int mid = (lo + hi) >> 1; if (tags[mid] < b) lo = mid + 1; else hi = mid; }
    int lo2 = lo, hi2 = nblk;
    while (lo2 < hi2) { int mid = (lo2 + hi2) >> 1; if (tags[mid] < b + 1) lo2 = mid + 1; else hi2 = mid; }
    float v = 0.f;
    for (int blk = lo; blk < lo2; blk++)
        v += part[(size_t)blk * CELLS + cell];
    const int idx = (b * 32 + k) * FP + f;
    const float tot = bacc[idx] + v;
    bacc[idx] = tot;
    if (f < 64) outp[OUT_OUT + ((b * 32 + k) << 6) + f] = tot;
}

// single block: mu + six scalars (unchanged)
__global__ void fin_k(const float* __restrict__ ws,
                      const float* __restrict__ amask,
                      float* __restrict__ outp) {
    const int t = threadIdx.x;
    const float* bacc = ws + WS_BACC;
    __shared__ float mu_s[BB * KK * 2];
    for (int idx = t; idx < BB * KK * 2; idx += 256) {
        int bk = idx >> 1, d = idx & 1;
        float v = bacc[bk * FP + 64 + d] / (bacc[bk * FP + 67] + EPS);
        mu_s[idx] = v;
        outp[OUT_MU + idx] = v;
    }
    __shared__ float kred[32][4];
    if (t < 32) {
        float S = 0, px = 0, py = 0, sq = 0;
        for (int b = 0; b < 16; b++) {
            const float* pp = bacc + (b * 32 + t) * FP;
            S += pp[67]; px += pp[64]; py += pp[65]; sq += pp[66];
        }
        float avg = S / (float)NN;
        float am = amask[t];
        float ssum = S + EPS;
        float mx = px / ssum, my = py / ssum;
        kred[t][0] = avg * __logf(avg + EPS);
        kred[t][1] = fabsf(avg * (1.f - am));
        kred[t][2] = sq / ssum - mx * mx - my * my;
        kred[t][3] = am;
    }
    __syncthreads();
    float sep = 0.f;
    for (int idx = t; idx < BB * KK * KK; idx += 256) {
        int b = idx >> 10, i = (idx >> 5) & 31, j = idx & 31;
        if (i != j) {
            float dx = mu_s[(b * 32 + i) * 2 + 0] - mu_s[(b * 32 + j) * 2 + 0];
            float dy = mu_s[(b * 32 + i) * 2 + 1] - mu_s[(b * 32 + j) * 2 + 1];
            sep += 1.f / (dx * dx + dy * dy + 1.f);
        }
    }
    __shared__ float red[256];
    red[t] = sep;
    __syncthreads();
    for (int s2 = 128; s2 > 0; s2 >>= 1) {
        if (t < s2) red[t] += red[t + s2];
        __syncthreads();
    }
    if (t == 0) {
        float div = 0, pru = 0, spa = 0, spar = 0;
        for (int kq = 0; kq < 32; kq++) {
            div += kred[kq][0]; pru += kred[kq][1];
            spa += kred[kq][2]; spar += kred[kq][3];
        }
        outp[OUT_SCAL + 0] = -ws[WS_ENT] / (float)NN;
        outp[OUT_SCAL + 1] = div;
        outp[OUT_SCAL + 2] = spa / 32.f;
        outp[OUT_SCAL + 3] = pru / 32.f;
        outp[OUT_SCAL + 4] = spar / 32.f;
        outp[OUT_SCAL + 5] = red[0] / (32.f * 31.f + EPS);
    }
}

extern "C" void kernel_launch(void* const* d_in, const int* in_sizes, int n_in,
                              void* d_out, int out_size, void* d_ws, size_t ws_size,
                              hipStream_t stream) {
    const float* x       = (const float*)d_in[0];
    const int*   batch   = (const int*)d_in[1];
    const float* pos     = (const float*)d_in[2];
    const float* u       = (const float*)d_in[3];
    const float* W1      = (const float*)d_in[4];
    const float* b1      = (const float*)d_in[5];
    const float* W2      = (const float*)d_in[6];
    const float* b2      = (const float*)d_in[7];
    const float* scaling = (const float*)d_in[8];
    const float* amask   = (const float*)d_in[9];
    float* outp = (float*)d_out;
    float* ws   = (float*)d_ws;

    int npb = 128;
    while (npb < NN &&
           ws_size < ((size_t)WS_PART + (size_t)(NN / npb) * CELLS) * sizeof(float))
        npb <<= 1;
    const int nblk = NN / npb;

    hipMemsetAsync(ws, 0, (size_t)(WS_BACC + WS_BACC_SZ) * sizeof(float), stream);
    prep_k<<<1, 256, 0, stream>>>(W1, W2, b2, scaling, amask, ws);
    node_k<<<NN / 64, 256, 0, stream>>>(x, u, b1, ws, outp + OUT_S, ws + WS_ENT);
    pool_k<<<nblk, 256, 0, stream>>>(outp + OUT_S, x, pos, batch,
                                     ws + WS_BACC, ws + WS_PART, (int*)(ws + WS_TAG), npb);
    reduce_k<<<dim3(BB, (CELLS + 255) / 256), 256, 0, stream>>>(
        ws + WS_PART, (const int*)(ws + WS_TAG), ws + WS_BACC, outp, nblk);
    fin_k<<<1, 256, 0, stream>>>(ws, amask, outp);
}